// Round 12
// baseline (105.436 us; speedup 1.0000x reference)
//
#include <hip/hip_runtime.h>

#define KS    7
#define H     256
#define W     256
#define STRIP 16                 // output rows per wave
#define WPB   4                  // waves per block (block covers 64 rows)
#define NSTEP (STRIP + KS - 1)   // 22 input rows per strip

typedef float vf4 __attribute__((ext_vector_type(4)));

// lane i <- lane i-1 (lane 0 -> 0): wave_shr:1, bound_ctrl=1
__device__ __forceinline__ float dpp_shr1(float x) {
    return __int_as_float(__builtin_amdgcn_mov_dpp(__float_as_int(x), 0x138, 0xf, 0xf, true));
}
// lane i <- lane i+1 (lane 63 -> 0): wave_shl:1, bound_ctrl=1
__device__ __forceinline__ float dpp_shl1(float x) {
    return __int_as_float(__builtin_amdgcn_mov_dpp(__float_as_int(x), 0x130, 0xf, 0xf, true));
}

// Build effective 7x7 kernel: w_eff = mk + noise*(noise_eps - mean(noise_eps))
__global__ void GaussianConvBlur_wprep(const float* __restrict__ weight,
                                       const float* __restrict__ noise,
                                       const float* __restrict__ noise_eps,
                                       float* __restrict__ wf) {
    int tid = threadIdx.x;
    if (tid < KS * KS) {
        float m = 0.f;
        #pragma unroll
        for (int i = 0; i < KS * KS; ++i) m += noise_eps[i];
        m *= (1.0f / (KS * KS));
        wf[tid] = weight[tid] + noise[0] * (noise_eps[tid] - m);
    }
}

// LDS-free depthwise 7x7: ring-8 fp32 accumulators; one aligned float4 load
// per step prefetched 3 ahead; DPP wave-shift halo; JLO/JHI dead-FMA trim;
// non-temporal stores; XCD-pairing swizzle (a plane's 4 blocks share an XCD).
__global__ __launch_bounds__(256) void GaussianConvBlur_conv(
        const float* __restrict__ in,
        const float* __restrict__ wfg,
        float* __restrict__ out) {
    const int lane = threadIdx.x & 63;
    const int wid  = threadIdx.x >> 6;

    // HW dispatch is round-robin over 8 XCDs by blockIdx. Map so the 4 blocks
    // of one plane are congruent mod 8 -> same XCD (L2 halo/plane locality).
    const int bid   = blockIdx.x;
    const int plane = (bid >> 5) * 8 + (bid & 7);
    const int sblk  = (bid >> 3) & 3;
    const int s0    = __builtin_amdgcn_readfirstlane((sblk * WPB + wid) * STRIP);

    const float* __restrict__ src = in  + (size_t)plane * (H * W);
    float*       __restrict__ dst = out + (size_t)plane * (H * W);

    // Pin the 49 uniform weights to SGPRs
    float wf[KS * KS];
    #pragma unroll
    for (int i = 0; i < KS * KS; ++i)
        wf[i] = __int_as_float(__builtin_amdgcn_readfirstlane(__float_as_int(wfg[i])));

    const int x4 = lane << 2;                   // aligned offset (floats)

    vf4 acc[8];
    #pragma unroll
    for (int i = 0; i < 8; ++i) acc[i] = (vf4)(0.f);

    vf4 pm[4];                                  // depth-3 prefetch ring

    #define LOADROW(REL, P) do {                                          \
        int ri_  = s0 - 3 + (REL);                                        \
        int ric_ = ri_ < 0 ? 0 : (ri_ > (H - 1) ? (H - 1) : ri_);         \
        pm[P] = *(const vf4*)(src + ric_ * W + x4);                       \
    } while (0)

    // j in [JLO,JHI]: at step REL only j >= 6-REL and j <= STRIP+5-REL feed
    // outputs this wave owns — trims dead FMAs at the strip boundaries.
    #define STEPBODY(REL, U, PF, JLO, JHI) do {                           \
        if (PF) LOADROW((REL) + 3, ((U) + 3) & 3);                        \
        const int ri = s0 - 3 + (REL);        /* uniform (SGPR) */        \
        if (ri >= 0 && ri < H) {              /* valid row: accumulate */ \
            vf4 r1 = pm[(U) & 3];                                         \
            float s[10];                                                  \
            s[0] = dpp_shr1(r1.y);            /* lane-1, lane0 -> 0 */    \
            s[1] = dpp_shr1(r1.z);                                        \
            s[2] = dpp_shr1(r1.w);                                        \
            s[3] = r1.x; s[4] = r1.y; s[5] = r1.z; s[6] = r1.w;           \
            s[7] = dpp_shl1(r1.x);            /* lane+1, lane63 -> 0 */   \
            s[8] = dpp_shl1(r1.y);                                        \
            s[9] = dpp_shl1(r1.z);                                        \
            _Pragma("unroll")                                             \
            for (int j = (JLO); j <= (JHI); ++j) {                        \
                const int slot = ((U) + j) & 7;    /* compile-time */     \
                const int ky   = 6 - j;                                   \
                _Pragma("unroll")                                         \
                for (int kx = 0; kx < 7; ++kx) {                          \
                    const float wv = wf[ky * 7 + kx];                     \
                    acc[slot].x = fmaf(wv, s[kx],     acc[slot].x);       \
                    acc[slot].y = fmaf(wv, s[kx + 1], acc[slot].y);       \
                    acc[slot].z = fmaf(wv, s[kx + 2], acc[slot].z);       \
                    acc[slot].w = fmaf(wv, s[kx + 3], acc[slot].w);       \
                }                                                         \
            }                                                             \
        }                                                                 \
        const int o = ri - 3;            /* this row completes now */     \
        if (o >= s0)                                                      \
            __builtin_nontemporal_store(acc[(U) & 7],                     \
                                        (vf4*)(dst + o * W + x4));        \
        acc[(U) & 7] = (vf4)(0.f);                                        \
    } while (0)

    LOADROW(0, 0);
    LOADROW(1, 1);
    LOADROW(2, 2);

    // warmup group: rel = 0..7, trim j < 6-rel
    #pragma unroll
    for (int u = 0; u < 8; ++u)
        STEPBODY(u, u, true, (u < 6 ? 6 - u : 0), 6);

    // full group: rel = 8..15
    #pragma unroll
    for (int u = 0; u < 8; ++u)
        STEPBODY(8 + u, u, true, 0, 6);

    // tail: rel = 16..21, trim j > 21-rel; last load is rel 21 (at u=2)
    #pragma unroll
    for (int u = 0; u < 6; ++u)
        STEPBODY(16 + u, u, (u < 3), 0, 5 - u);

    #undef LOADROW
    #undef STEPBODY
}

extern "C" void kernel_launch(void* const* d_in, const int* in_sizes, int n_in,
                              void* d_out, int out_size, void* d_ws, size_t ws_size,
                              hipStream_t stream) {
    const float* x         = (const float*)d_in[0];  // (16,64,256,256)
    const float* weight    = (const float*)d_in[1];  // (64,64,7,7)
    const float* noise     = (const float*)d_in[2];  // scalar
    const float* noise_eps = (const float*)d_in[3];  // (7,7)
    float*       out       = (float*)d_out;
    float*       wf        = (float*)d_ws;           // 49 floats scratch

    GaussianConvBlur_wprep<<<1, 64, 0, stream>>>(weight, noise, noise_eps, wf);

    const int planes = 16 * 64;                       // 1024 planes
    GaussianConvBlur_conv<<<planes * 4, 256, 0, stream>>>(x, wf, out);
}

// Round 13
// 97.749 us; speedup vs baseline: 1.0786x; 1.0786x over previous
//
#include <hip/hip_runtime.h>

#define KS    7
#define H     256
#define W     256
#define STRIP 32                 // output rows per wave
#define WPB   4                  // waves per block (block covers 128 rows)
#define NSTEP (STRIP + KS - 1)   // 38 input rows per strip

typedef float vf4 __attribute__((ext_vector_type(4)));

// lane i <- lane i-1 (lane 0 -> 0): wave_shr:1, bound_ctrl=1
__device__ __forceinline__ float dpp_shr1(float x) {
    return __int_as_float(__builtin_amdgcn_mov_dpp(__float_as_int(x), 0x138, 0xf, 0xf, true));
}
// lane i <- lane i+1 (lane 63 -> 0): wave_shl:1, bound_ctrl=1
__device__ __forceinline__ float dpp_shl1(float x) {
    return __int_as_float(__builtin_amdgcn_mov_dpp(__float_as_int(x), 0x130, 0xf, 0xf, true));
}

// Build effective 7x7 kernel: w_eff = mk + noise*(noise_eps - mean(noise_eps))
__global__ void GaussianConvBlur_wprep(const float* __restrict__ weight,
                                       const float* __restrict__ noise,
                                       const float* __restrict__ noise_eps,
                                       float* __restrict__ wf) {
    int tid = threadIdx.x;
    if (tid < KS * KS) {
        float m = 0.f;
        #pragma unroll
        for (int i = 0; i < KS * KS; ++i) m += noise_eps[i];
        m *= (1.0f / (KS * KS));
        wf[tid] = weight[tid] + noise[0] * (noise_eps[tid] - m);
    }
}

// LDS-free depthwise 7x7 (round-11 structure): ring-8 fp32 accumulators; one
// aligned float4 load per step prefetched 3 ahead; DPP wave-shift halo;
// JLO/JHI dead-FMA trim; non-temporal stores. NEW: only 32 weights pinned to
// SGPRs, 17 pinned to VGPRs — keeps SGPR alloc <= 96 so 8 waves/SIMD fit
// (SGPR file 800/SIMD; 112 SGPRs capped residency at 7 waves/SIMD).
__global__ __launch_bounds__(256) void GaussianConvBlur_conv(
        const float* __restrict__ in,
        const float* __restrict__ wfg,
        float* __restrict__ out) {
    const int lane = threadIdx.x & 63;
    const int wid  = threadIdx.x >> 6;

    const int plane = blockIdx.x >> 1;          // 2 blocks per plane
    const int sblk  = blockIdx.x & 1;
    const int s0    = __builtin_amdgcn_readfirstlane((sblk * WPB + wid) * STRIP);

    const float* __restrict__ src = in  + (size_t)plane * (H * W);
    float*       __restrict__ dst = out + (size_t)plane * (H * W);

    // Weights: 32 in SGPRs (free scalar operand), 17 pinned to VGPRs so the
    // SGPR allocation stays within the 8-waves/SIMD budget (<=100/wave).
    float wf[KS * KS];
    #pragma unroll
    for (int i = 0; i < KS * KS; ++i) {
        float v = wfg[i];
        if (i < 32) {
            wf[i] = __int_as_float(__builtin_amdgcn_readfirstlane(__float_as_int(v)));
        } else {
            asm volatile("" : "+v"(v));   // pin to VGPR, block SGPR promotion
            wf[i] = v;
        }
    }

    const int x4 = lane << 2;                   // aligned offset (floats)

    vf4 acc[8];
    #pragma unroll
    for (int i = 0; i < 8; ++i) acc[i] = (vf4)(0.f);

    vf4 pm[4];                                  // depth-3 prefetch ring

    #define LOADROW(REL, P) do {                                          \
        int ri_  = s0 - 3 + (REL);                                        \
        int ric_ = ri_ < 0 ? 0 : (ri_ > (H - 1) ? (H - 1) : ri_);         \
        pm[P] = *(const vf4*)(src + ric_ * W + x4);                       \
    } while (0)

    // j in [JLO,JHI]: at step REL only j >= 6-REL and j <= STRIP+5-REL feed
    // outputs this wave owns — trims dead FMAs at the strip boundaries.
    #define STEPBODY(REL, U, PF, JLO, JHI) do {                           \
        if (PF) LOADROW((REL) + 3, ((U) + 3) & 3);                        \
        const int ri = s0 - 3 + (REL);        /* uniform (SGPR) */        \
        if (ri >= 0 && ri < H) {              /* valid row: accumulate */ \
            vf4 r1 = pm[(U) & 3];                                         \
            float s[10];                                                  \
            s[0] = dpp_shr1(r1.y);            /* lane-1, lane0 -> 0 */    \
            s[1] = dpp_shr1(r1.z);                                        \
            s[2] = dpp_shr1(r1.w);                                        \
            s[3] = r1.x; s[4] = r1.y; s[5] = r1.z; s[6] = r1.w;           \
            s[7] = dpp_shl1(r1.x);            /* lane+1, lane63 -> 0 */   \
            s[8] = dpp_shl1(r1.y);                                        \
            s[9] = dpp_shl1(r1.z);                                        \
            _Pragma("unroll")                                             \
            for (int j = (JLO); j <= (JHI); ++j) {                        \
                const int slot = ((U) + j) & 7;    /* compile-time */     \
                const int ky   = 6 - j;                                   \
                _Pragma("unroll")                                         \
                for (int kx = 0; kx < 7; ++kx) {                          \
                    const float wv = wf[ky * 7 + kx];                     \
                    acc[slot].x = fmaf(wv, s[kx],     acc[slot].x);       \
                    acc[slot].y = fmaf(wv, s[kx + 1], acc[slot].y);       \
                    acc[slot].z = fmaf(wv, s[kx + 2], acc[slot].z);       \
                    acc[slot].w = fmaf(wv, s[kx + 3], acc[slot].w);       \
                }                                                         \
            }                                                             \
        }                                                                 \
        const int o = ri - 3;            /* this row completes now */     \
        if (o >= s0)                                                      \
            __builtin_nontemporal_store(acc[(U) & 7],                     \
                                        (vf4*)(dst + o * W + x4));        \
        acc[(U) & 7] = (vf4)(0.f);                                        \
    } while (0)

    LOADROW(0, 0);
    LOADROW(1, 1);
    LOADROW(2, 2);

    // warmup group: rel = 0..7, trim j < 6-rel
    #pragma unroll
    for (int u = 0; u < 8; ++u)
        STEPBODY(u, u, true, (u < 6 ? 6 - u : 0), 6);

    // full groups: rel = 8..31 (3 groups of 8; ring indices stay aligned)
    for (int g = 1; g < 4; ++g) {
        #pragma unroll
        for (int u = 0; u < 8; ++u)
            STEPBODY(g * 8 + u, u, true, 0, 6);
    }

    // tail: rel = 32..37, trim j > 37-rel; last load is rel 37 (at u=2)
    #pragma unroll
    for (int u = 0; u < 6; ++u)
        STEPBODY(32 + u, u, (u < 3), 0, 5 - u);

    #undef LOADROW
    #undef STEPBODY
}

extern "C" void kernel_launch(void* const* d_in, const int* in_sizes, int n_in,
                              void* d_out, int out_size, void* d_ws, size_t ws_size,
                              hipStream_t stream) {
    const float* x         = (const float*)d_in[0];  // (16,64,256,256)
    const float* weight    = (const float*)d_in[1];  // (64,64,7,7)
    const float* noise     = (const float*)d_in[2];  // scalar
    const float* noise_eps = (const float*)d_in[3];  // (7,7)
    float*       out       = (float*)d_out;
    float*       wf        = (float*)d_ws;           // 49 floats scratch

    GaussianConvBlur_wprep<<<1, 64, 0, stream>>>(weight, noise, noise_eps, wf);

    const int planes = 16 * 64;                       // 1024 planes
    GaussianConvBlur_conv<<<planes * 2, 256, 0, stream>>>(x, wf, out);
}

// Round 14
// 95.771 us; speedup vs baseline: 1.1009x; 1.0207x over previous
//
#include <hip/hip_runtime.h>

#define KS    7
#define H     256
#define W     256
#define STRIP 32                 // output rows per wave
#define WPB   2                  // waves per block (block covers 64 rows)
#define NSTEP (STRIP + KS - 1)   // 38 input rows per strip

typedef float vf4 __attribute__((ext_vector_type(4)));

// lane i <- lane i-1 (lane 0 -> 0): wave_shr:1, bound_ctrl=1
__device__ __forceinline__ float dpp_shr1(float x) {
    return __int_as_float(__builtin_amdgcn_mov_dpp(__float_as_int(x), 0x138, 0xf, 0xf, true));
}
// lane i <- lane i+1 (lane 63 -> 0): wave_shl:1, bound_ctrl=1
__device__ __forceinline__ float dpp_shl1(float x) {
    return __int_as_float(__builtin_amdgcn_mov_dpp(__float_as_int(x), 0x130, 0xf, 0xf, true));
}

// Build effective 7x7 kernel: w_eff = mk + noise*(noise_eps - mean(noise_eps))
__global__ void GaussianConvBlur_wprep(const float* __restrict__ weight,
                                       const float* __restrict__ noise,
                                       const float* __restrict__ noise_eps,
                                       float* __restrict__ wf) {
    int tid = threadIdx.x;
    if (tid < KS * KS) {
        float m = 0.f;
        #pragma unroll
        for (int i = 0; i < KS * KS; ++i) m += noise_eps[i];
        m *= (1.0f / (KS * KS));
        wf[tid] = weight[tid] + noise[0] * (noise_eps[tid] - m);
    }
}

// LDS-free depthwise 7x7 (round-11 core): ring-8 fp32 accumulators; one
// aligned float4 load per step prefetched 3 ahead; DPP wave-shift halo;
// JLO/JHI dead-FMA trim; non-temporal stores. NEW: 128-thread blocks
// (WPB=2) — same per-wave work & traffic, finer dispatch quanta (4096
// blocks, 16 blocks/CU) for ramp/tail packing.
__global__ __launch_bounds__(128) void GaussianConvBlur_conv(
        const float* __restrict__ in,
        const float* __restrict__ wfg,
        float* __restrict__ out) {
    const int lane = threadIdx.x & 63;
    const int wid  = threadIdx.x >> 6;

    const int plane = blockIdx.x >> 2;          // 4 blocks per plane
    const int sblk  = blockIdx.x & 3;
    const int s0    = __builtin_amdgcn_readfirstlane((sblk * WPB + wid) * STRIP);

    const float* __restrict__ src = in  + (size_t)plane * (H * W);
    float*       __restrict__ dst = out + (size_t)plane * (H * W);

    // Pin the 49 uniform weights to SGPRs
    float wf[KS * KS];
    #pragma unroll
    for (int i = 0; i < KS * KS; ++i)
        wf[i] = __int_as_float(__builtin_amdgcn_readfirstlane(__float_as_int(wfg[i])));

    const int x4 = lane << 2;                   // aligned offset (floats)

    vf4 acc[8];
    #pragma unroll
    for (int i = 0; i < 8; ++i) acc[i] = (vf4)(0.f);

    vf4 pm[4];                                  // depth-3 prefetch ring

    #define LOADROW(REL, P) do {                                          \
        int ri_  = s0 - 3 + (REL);                                        \
        int ric_ = ri_ < 0 ? 0 : (ri_ > (H - 1) ? (H - 1) : ri_);         \
        pm[P] = *(const vf4*)(src + ric_ * W + x4);                       \
    } while (0)

    // j in [JLO,JHI]: at step REL only j >= 6-REL and j <= STRIP+5-REL feed
    // outputs this wave owns — trims dead FMAs at the strip boundaries.
    #define STEPBODY(REL, U, PF, JLO, JHI) do {                           \
        if (PF) LOADROW((REL) + 3, ((U) + 3) & 3);                        \
        const int ri = s0 - 3 + (REL);        /* uniform (SGPR) */        \
        if (ri >= 0 && ri < H) {              /* valid row: accumulate */ \
            vf4 r1 = pm[(U) & 3];                                         \
            float s[10];                                                  \
            s[0] = dpp_shr1(r1.y);            /* lane-1, lane0 -> 0 */    \
            s[1] = dpp_shr1(r1.z);                                        \
            s[2] = dpp_shr1(r1.w);                                        \
            s[3] = r1.x; s[4] = r1.y; s[5] = r1.z; s[6] = r1.w;           \
            s[7] = dpp_shl1(r1.x);            /* lane+1, lane63 -> 0 */   \
            s[8] = dpp_shl1(r1.y);                                        \
            s[9] = dpp_shl1(r1.z);                                        \
            _Pragma("unroll")                                             \
            for (int j = (JLO); j <= (JHI); ++j) {                        \
                const int slot = ((U) + j) & 7;    /* compile-time */     \
                const int ky   = 6 - j;                                   \
                _Pragma("unroll")                                         \
                for (int kx = 0; kx < 7; ++kx) {                          \
                    const float wv = wf[ky * 7 + kx];                     \
                    acc[slot].x = fmaf(wv, s[kx],     acc[slot].x);       \
                    acc[slot].y = fmaf(wv, s[kx + 1], acc[slot].y);       \
                    acc[slot].z = fmaf(wv, s[kx + 2], acc[slot].z);       \
                    acc[slot].w = fmaf(wv, s[kx + 3], acc[slot].w);       \
                }                                                         \
            }                                                             \
        }                                                                 \
        const int o = ri - 3;            /* this row completes now */     \
        if (o >= s0)                                                      \
            __builtin_nontemporal_store(acc[(U) & 7],                     \
                                        (vf4*)(dst + o * W + x4));        \
        acc[(U) & 7] = (vf4)(0.f);                                        \
    } while (0)

    LOADROW(0, 0);
    LOADROW(1, 1);
    LOADROW(2, 2);

    // warmup group: rel = 0..7, trim j < 6-rel
    #pragma unroll
    for (int u = 0; u < 8; ++u)
        STEPBODY(u, u, true, (u < 6 ? 6 - u : 0), 6);

    // full groups: rel = 8..31 (3 groups of 8; ring indices stay aligned)
    for (int g = 1; g < 4; ++g) {
        #pragma unroll
        for (int u = 0; u < 8; ++u)
            STEPBODY(g * 8 + u, u, true, 0, 6);
    }

    // tail: rel = 32..37, trim j > 37-rel; last load is rel 37 (at u=2)
    #pragma unroll
    for (int u = 0; u < 6; ++u)
        STEPBODY(32 + u, u, (u < 3), 0, 5 - u);

    #undef LOADROW
    #undef STEPBODY
}

extern "C" void kernel_launch(void* const* d_in, const int* in_sizes, int n_in,
                              void* d_out, int out_size, void* d_ws, size_t ws_size,
                              hipStream_t stream) {
    const float* x         = (const float*)d_in[0];  // (16,64,256,256)
    const float* weight    = (const float*)d_in[1];  // (64,64,7,7)
    const float* noise     = (const float*)d_in[2];  // scalar
    const float* noise_eps = (const float*)d_in[3];  // (7,7)
    float*       out       = (float*)d_out;
    float*       wf        = (float*)d_ws;           // 49 floats scratch

    GaussianConvBlur_wprep<<<1, 64, 0, stream>>>(weight, noise, noise_eps, wf);

    const int planes = 16 * 64;                       // 1024 planes
    GaussianConvBlur_conv<<<planes * 4, 128, 0, stream>>>(x, wf, out);
}